// Round 4
// baseline (8888.713 us; speedup 1.0000x reference)
//
#include <hip/hip_runtime.h>
#include <hip/hip_cooperative_groups.h>
#include <math.h>

namespace cg = cooperative_groups;

#define N 2048
#define DIM 128
#define CAP (N*64)
#define LOGN 7.6246189861593985f

typedef unsigned long long u64;
typedef unsigned int u32;

// ---------------------------------------------------------------- precompute

__global__ __launch_bounds__(256) void k_init(double* k1acc, double* smfs) {
  if (threadIdx.x == 0) { *k1acc = 0.0; *smfs = 0.0; }
}

// inter = exp(-(A @ B^T)), accumulate k1 = sum(inter)
__global__ __launch_bounds__(256) void k_gemm_inter(
    const float* __restrict__ A, const float* __restrict__ B,
    float* __restrict__ O, double* __restrict__ k1acc) {
  __shared__ __align__(16) float As[64][65];
  __shared__ __align__(16) float Bs[64][65];
  __shared__ float red[256];
  const int t = threadIdx.x;
  const int i0 = blockIdx.y * 64, j0 = blockIdx.x * 64;
  const int tx = t & 15, ty = t >> 4;
  float acc[4][4] = {};
  for (int kk = 0; kk < DIM; kk += 64) {
    if (kk) __syncthreads();
    for (int q = t; q < 64 * 16; q += 256) {
      int row = q >> 4, k4 = (q & 15) << 2;
      float4 av = *(const float4*)&A[(size_t)(i0 + row) * DIM + kk + k4];
      As[k4 + 0][row] = av.x; As[k4 + 1][row] = av.y;
      As[k4 + 2][row] = av.z; As[k4 + 3][row] = av.w;
      float4 bv = *(const float4*)&B[(size_t)(j0 + row) * DIM + kk + k4];
      Bs[k4 + 0][row] = bv.x; Bs[k4 + 1][row] = bv.y;
      Bs[k4 + 2][row] = bv.z; Bs[k4 + 3][row] = bv.w;
    }
    __syncthreads();
    #pragma unroll 4
    for (int k = 0; k < 64; ++k) {
      float av[4], bv[4];
      #pragma unroll
      for (int d = 0; d < 4; ++d) { av[d] = As[k][ty * 4 + d]; bv[d] = Bs[k][tx * 4 + d]; }
      #pragma unroll
      for (int di = 0; di < 4; ++di)
        #pragma unroll
        for (int dj = 0; dj < 4; ++dj)
          acc[di][dj] = fmaf(av[di], bv[dj], acc[di][dj]);
    }
  }
  float psum = 0.f;
  #pragma unroll
  for (int di = 0; di < 4; ++di)
    #pragma unroll
    for (int dj = 0; dj < 4; ++dj) {
      float vv = __expf(-acc[di][dj]);
      O[(size_t)(i0 + ty * 4 + di) * N + (j0 + tx * 4 + dj)] = vv;
      psum += vv;
    }
  red[t] = psum; __syncthreads();
  for (int off = 128; off; off >>= 1) { if (t < off) red[t] += red[t + off]; __syncthreads(); }
  if (t == 0) atomicAdd(k1acc, (double)red[0]);
}

__global__ __launch_bounds__(256) void k_count(const float* __restrict__ adj, int* __restrict__ cnt) {
  int i = blockIdx.x * 4 + (threadIdx.x >> 6);
  int lane = threadIdx.x & 63;
  const float* row = adj + (size_t)i * N;
  int c = 0;
  for (int j = lane; j < N; j += 64) c += (row[j] != 0.f) ? 1 : 0;
  for (int off = 32; off; off >>= 1) c += __shfl_down(c, off);
  if (lane == 0) cnt[i] = c;
}

__global__ __launch_bounds__(256) void k_scan(const int* __restrict__ cnt, int* __restrict__ rp) {
  __shared__ int sums[256];
  int t = threadIdx.x;
  int local[8]; int run = 0;
  int base = t * 8;
  #pragma unroll
  for (int k = 0; k < 8; ++k) { local[k] = run; run += cnt[base + k]; }
  sums[t] = run; __syncthreads();
  for (int off = 1; off < 256; off <<= 1) {
    int val = (t >= off) ? sums[t - off] : 0;
    __syncthreads();
    sums[t] += val;
    __syncthreads();
  }
  int pre = (t == 0) ? 0 : sums[t - 1];
  #pragma unroll
  for (int k = 0; k < 8; ++k) rp[base + k] = pre + local[k];
  if (t == 255) rp[N] = sums[255];
}

__global__ __launch_bounds__(256) void k_fill(const float* __restrict__ adj, const int* __restrict__ rp,
                                              int* __restrict__ cols, int* __restrict__ rows) {
  int i = blockIdx.x * 4 + (threadIdx.x >> 6);
  int lane = threadIdx.x & 63;
  const float* row = adj + (size_t)i * N;
  int pos = rp[i];
  for (int j0 = 0; j0 < N; j0 += 64) {
    bool p = row[j0 + lane] != 0.f;
    u64 mask = __ballot(p);
    if (p) {
      int off = __popcll(mask & ((1ull << lane) - 1ull));
      cols[pos + off] = j0 + lane;
      rows[pos + off] = i;
    }
    pos += __popcll(mask);
  }
}

// vals[p] = exp(-dot(emb[rows[p]], emb[cols[p]]))
__global__ __launch_bounds__(256) void k_vals(const int* __restrict__ rp, const int* __restrict__ rows,
                                              const int* __restrict__ cols, float* __restrict__ vals,
                                              const float* __restrict__ emb) {
  int p = blockIdx.x * 4 + (threadIdx.x >> 6);
  int lane = threadIdx.x & 63;
  int total = rp[N];
  if (p >= total) return;
  int i = rows[p], k = cols[p];
  const float* ei = emb + (size_t)i * DIM;
  const float* ek = emb + (size_t)k * DIM;
  float s = ei[lane] * ek[lane] + ei[lane + 64] * ek[lane + 64];
  for (int off = 32; off; off >>= 1) s += __shfl_down(s, off);
  if (lane == 0) vals[p] = __expf(-s);
}

__global__ __launch_bounds__(256) void k_rowstats(const int* __restrict__ rp, const float* __restrict__ vals,
                                                  float* __restrict__ rs, float* __restrict__ rsq) {
  int i = blockIdx.x * 4 + (threadIdx.x >> 6);
  int lane = threadIdx.x & 63;
  int p0 = rp[i], p1 = rp[i + 1];
  float s1 = 0.f, s2 = 0.f;
  for (int p = p0 + lane; p < p1; p += 64) { float w = vals[p]; s1 += w; s2 += w * w; }
  for (int off = 32; off; off >>= 1) { s1 += __shfl_down(s1, off); s2 += __shfl_down(s2, off); }
  if (lane == 0) { rs[i] = s1; rsq[i] = s2; }
}

// ---------------------------------------------------------------- spmm v2
// Out[c][i0..i0+8] = (csr @ S)^T slice. CSR window staged in LDS (cols pre-*N).
// One column per thread; 8-row panel; each thread's 8 results = its contiguous
// output row segment -> no transpose needed. tile = bid&7 pins c-slice to XCD.
__global__ __launch_bounds__(256) void k_spmmt(const int* __restrict__ rp, const int* __restrict__ cols,
                                               const float* __restrict__ vals, const float* __restrict__ S,
                                               float* __restrict__ Out) {
  __shared__ int winc[1024];
  __shared__ float winv[1024];
  __shared__ int rb[9];
  const int t = threadIdx.x;
  const int tile = blockIdx.x & 7;
  const int c = tile * 256 + t;
  const int i0 = (blockIdx.x >> 3) * 8;
  const int p0 = rp[i0];
  if (t < 9) rb[t] = rp[i0 + t] - p0;
  __syncthreads();
  const int nn = rb[8];
  for (int k = t; k < nn; k += 256) {
    winc[k] = cols[p0 + k] << 11;     // *N
    winv[k] = vals[p0 + k];
  }
  __syncthreads();
  float a[8];
  #pragma unroll
  for (int r = 0; r < 8; ++r) {
    int pe = rb[r + 1];
    int p = rb[r];
    float a0 = 0.f, a1 = 0.f, a2 = 0.f, a3 = 0.f;
    for (; p + 3 < pe; p += 4) {
      a0 = fmaf(winv[p],     S[winc[p]     + c], a0);
      a1 = fmaf(winv[p + 1], S[winc[p + 1] + c], a1);
      a2 = fmaf(winv[p + 2], S[winc[p + 2] + c], a2);
      a3 = fmaf(winv[p + 3], S[winc[p + 3] + c], a3);
    }
    for (; p < pe; ++p) a0 = fmaf(winv[p], S[winc[p] + c], a0);
    a[r] = (a0 + a1) + (a2 + a3);
  }
  size_t ob = (size_t)(tile * 256 + t) * N + i0;
  *(float4*)&Out[ob]     = make_float4(a[0], a[1], a[2], a[3]);
  *(float4*)&Out[ob + 4] = make_float4(a[4], a[5], a[6], a[7]);
}

// ---------------------------------------------------------------- cooperative outer iteration
// Fuses: prep (Ai/Bj/RLi) + K build into LDS + 5 sinkhorn iters + s write + marginals.
// 512 blocks x 256 threads; block owns rows r0=4b..4b+4 of K; 49.2 KB LDS -> 2 blocks/CU.
__global__ __launch_bounds__(256, 2) void k_coop(
    const float* __restrict__ inter, const float* __restrict__ M, float* __restrict__ s,
    const int* __restrict__ rp1, const int* __restrict__ cols1, const float* __restrict__ vals1,
    const int* __restrict__ rp2, const int* __restrict__ cols2, const float* __restrict__ vals2,
    const float* __restrict__ r1sq, const float* __restrict__ rs1,
    const float* __restrict__ r2sq, const float* __restrict__ rs2,
    float* __restrict__ as_, float* __restrict__ bs_, const float* __restrict__ lamp,
    float* __restrict__ Ai, float* __restrict__ Bj, float* __restrict__ RLi,
    float* __restrict__ vglob, float* __restrict__ part, float* __restrict__ bsp,
    int hasM) {
  cg::grid_group grid = cg::this_grid();
  __shared__ __align__(16) float Ks[4 * N];   // 32 KB
  __shared__ __align__(16) float vs[N];       // 8 KB
  __shared__ __align__(16) float bc[N];       // 8 KB
  __shared__ float us4[4], aih[4], rlih[4], red4[4];
  const int b = blockIdx.x, t = threadIdx.x;
  const int r0 = b * 4;
  const float lam = *lamp;

  // ---- phase 0: prep (blocks 0..23 cover 3*2048 sites; only 2*2048 used)
  if (b < 16) {
    int g = b * 256 + t;
    if (!hasM) {
      float f = 0.00048828125f - lam * 2048.f;
      if (g < N) {
        Ai[g] = -2000.f * r1sq[g] * f;
        RLi[g] = 4000.f * rs1[g] * (2.384185791015625e-07f - lam);
      } else {
        int j = g - N;
        Bj[j] = -2000.f * r2sq[j] * f;
      }
    } else {
      if (g < N) {
        int q0 = rp1[g], q1 = rp1[g + 1];
        float acc = 0.f;
        for (int p = q0; p < q1; ++p) { float w = vals1[p]; acc = fmaf(w * w, as_[cols1[p]], acc); }
        Ai[g] = -2000.f * (acc - lam * 2048.f * r1sq[g]);
        RLi[g] = -4000.f * lam * rs1[g];
      } else {
        int j = g - N;
        int q0 = rp2[j], q1 = rp2[j + 1];
        float acc = 0.f;
        for (int p = q0; p < q1; ++p) { float w = vals2[p]; acc = fmaf(w * w, bs_[cols2[p]], acc); }
        Bj[j] = -2000.f * (acc - lam * 2048.f * r2sq[j]);
      }
    }
  }
  grid.sync();

  // ---- phase 1: K rows r0..r0+4 into LDS
  if (t < 4) { aih[t] = Ai[r0 + t]; rlih[t] = RLi[r0 + t]; }
  __syncthreads();
  for (int q = 0; q < 8; ++q) {
    int j = q * 256 + t;
    float bv = Bj[j], r2 = rs2[j];
    #pragma unroll
    for (int r = 0; r < 4; ++r) {
      size_t idx = (size_t)(r0 + r) * N + j;
      float kv = fmaf(-100.f, inter[idx], aih[r] + bv + rlih[r] * r2);
      if (hasM) kv = fmaf(4000.f, M[idx], kv);
      Ks[r * N + j] = kv;
    }
    vs[j] = 0.f;
  }
  __syncthreads();

  const int w = t >> 6, lane = t & 63;
  // ---- 5 sinkhorn iterations
  for (int it = 0; it < 5; ++it) {
    // row LSE: wave w owns row w
    {
      float m = -INFINITY, ss = 0.f;
      const float* Kr = Ks + w * N;
      #pragma unroll
      for (int q = 0; q < 8; ++q) {
        int j = lane * 4 + q * 256;
        float4 kv = *(const float4*)&Kr[j];
        float4 vv4 = *(const float4*)&vs[j];
        float x0 = kv.x + vv4.x, x1 = kv.y + vv4.y, x2 = kv.z + vv4.z, x3 = kv.w + vv4.w;
        float mx = fmaxf(fmaxf(x0, x1), fmaxf(x2, x3));
        float nm = fmaxf(m, mx);
        ss = ss * __expf(m - nm) + __expf(x0 - nm) + __expf(x1 - nm)
                                 + __expf(x2 - nm) + __expf(x3 - nm);
        m = nm;
      }
      for (int off = 32; off; off >>= 1) {
        float mo = __shfl_xor(m, off), so = __shfl_xor(ss, off);
        float nm = fmaxf(m, mo);
        ss = ss * __expf(m - nm) + so * __expf(mo - nm);
        m = nm;
      }
      if (lane == 0) us4[w] = -LOGN - (m + __logf(ss));
    }
    __syncthreads();
    // column partials over own 4 rows
    {
      float u0 = us4[0], u1 = us4[1], u2 = us4[2], u3 = us4[3];
      #pragma unroll
      for (int q = 0; q < 8; ++q) {
        int c = q * 256 + t;
        float x0 = Ks[c] + u0, x1 = Ks[N + c] + u1;
        float x2 = Ks[2 * N + c] + u2, x3 = Ks[3 * N + c] + u3;
        float m = fmaxf(fmaxf(x0, x1), fmaxf(x2, x3));
        float ss = __expf(x0 - m) + __expf(x1 - m) + __expf(x2 - m) + __expf(x3 - m);
        part[(size_t)b * N + c] = m + __logf(ss);
      }
    }
    grid.sync();
    // combine 512 stripes for 4 owned columns
    {
      int col = b * 4 + w;
      float m = -INFINITY, ss = 0.f;
      #pragma unroll
      for (int k8 = 0; k8 < 8; ++k8) {
        float x = part[(size_t)(lane * 8 + k8) * N + col];
        float nm = fmaxf(m, x);
        ss = ss * __expf(m - nm) + __expf(x - nm);
        m = nm;
      }
      for (int off = 32; off; off >>= 1) {
        float mo = __shfl_xor(m, off), so = __shfl_xor(ss, off);
        float nm = fmaxf(m, mo);
        ss = ss * __expf(m - nm) + so * __expf(mo - nm);
        m = nm;
      }
      if (lane == 0) vglob[col] = -LOGN - (m + __logf(ss));
    }
    grid.sync();
    // reload vs
    #pragma unroll
    for (int q = 0; q < 2; ++q) {
      int j = (q * 256 + t) * 4;
      *(float4*)&vs[j] = *(const float4*)&vglob[j];
    }
    __syncthreads();
  }

  // ---- s write + marginals
  for (int q = 0; q < 8; ++q) bc[q * 256 + t] = 0.f;
  __syncthreads();
  for (int r = 0; r < 4; ++r) {
    float ui = us4[r];
    float* sr = s + (size_t)(r0 + r) * N;
    float rsum = 0.f;
    #pragma unroll
    for (int q = 0; q < 8; ++q) {
      int j = q * 256 + t;
      float sv = __expf(Ks[r * N + j] + ui + vs[j]);
      sr[j] = sv;
      rsum += sv;
      bc[j] += sv;
    }
    for (int off = 32; off; off >>= 1) rsum += __shfl_down(rsum, off);
    if (lane == 0) red4[w] = rsum;
    __syncthreads();
    if (t == 0) as_[r0 + r] = red4[0] + red4[1] + red4[2] + red4[3];
    __syncthreads();
  }
  for (int q = 0; q < 8; ++q) {
    int c = q * 256 + t;
    bsp[(size_t)b * N + c] = bc[c];
  }
  grid.sync();
  {
    int col = b * 4 + w;
    float ssum = 0.f;
    #pragma unroll
    for (int k8 = 0; k8 < 8; ++k8) ssum += bsp[(size_t)(lane * 8 + k8) * N + col];
    for (int off = 32; off; off >>= 1) ssum += __shfl_down(ssum, off);
    if (lane == 0) bs_[col] = ssum;
  }
}

// ---------------------------------------------------------------- final

// mode 2 only: raw pa/pb for the loss
__global__ __launch_bounds__(256) void k_prep2(
    const int* __restrict__ rp1, const int* __restrict__ cols1, const float* __restrict__ vals1,
    const int* __restrict__ rp2, const int* __restrict__ cols2, const float* __restrict__ vals2,
    const float* __restrict__ as_, const float* __restrict__ bs_,
    float* __restrict__ paf, float* __restrict__ pbf) {
  int g = blockIdx.x * 256 + threadIdx.x;
  if (g < N) {
    int p0 = rp1[g], p1 = rp1[g + 1];
    float acc = 0.f;
    for (int p = p0; p < p1; ++p) { float w = vals1[p]; acc = fmaf(w * w, as_[cols1[p]], acc); }
    paf[g] = acc;
  } else if (g < 2 * N) {
    int j = g - N;
    int p0 = rp2[j], p1 = rp2[j + 1];
    float acc = 0.f;
    for (int p = p0; p < p1; ++p) { float w = vals2[p]; acc = fmaf(w * w, bs_[cols2[p]], acc); }
    pbf[j] = acc;
  }
}

__global__ __launch_bounds__(256) void k_rowdots(const float* __restrict__ inter, const float* __restrict__ s,
                                                 const float* __restrict__ rs2, float* __restrict__ sisr,
                                                 float* __restrict__ yv) {
  __shared__ __align__(16) float r2[N];
  int t = threadIdx.x;
  for (int j = t * 4; j < N; j += 1024) *(float4*)&r2[j] = *(const float4*)&rs2[j];
  __syncthreads();
  int lane = t & 63;
  int i = blockIdx.x * 4 + (t >> 6);
  const float* ir = inter + (size_t)i * N;
  const float* sr = s + (size_t)i * N;
  float d1 = 0.f, d2 = 0.f;
  for (int j = lane * 4; j < N; j += 256) {
    float4 iv = *(const float4*)&ir[j];
    float4 sv = *(const float4*)&sr[j];
    d1 += iv.x * sv.x + iv.y * sv.y + iv.z * sv.z + iv.w * sv.w;
    d2 += sv.x * r2[j] + sv.y * r2[j + 1] + sv.z * r2[j + 2] + sv.w * r2[j + 3];
  }
  for (int off = 32; off; off >>= 1) { d1 += __shfl_down(d1, off); d2 += __shfl_down(d2, off); }
  if (lane == 0) { sisr[i] = d1; yv[i] = d2; }
}

// smfs += sum(M .* s), both row-major
__global__ __launch_bounds__(256) void k_dotMS(const float* __restrict__ M, const float* __restrict__ s,
                                               double* __restrict__ acc) {
  __shared__ double red[256];
  int t = threadIdx.x;
  size_t base = ((size_t)blockIdx.x * 256 + t) * 4;
  float4 mv = *(const float4*)&M[base];
  float4 sv = *(const float4*)&s[base];
  double a = (double)(mv.x * sv.x) + (double)(mv.y * sv.y)
           + (double)(mv.z * sv.z) + (double)(mv.w * sv.w);
  red[t] = a; __syncthreads();
  for (int off = 128; off; off >>= 1) { if (t < off) red[t] += red[t + off]; __syncthreads(); }
  if (t == 0) atomicAdd(acc, red[0]);
}

__global__ __launch_bounds__(256) void k_final(
    const float* __restrict__ paf, const float* __restrict__ pbf,
    const float* __restrict__ r1sq, const float* __restrict__ r2sq,
    const float* __restrict__ rs1, const float* __restrict__ rs2,
    const float* __restrict__ as_, const float* __restrict__ bs_,
    const float* __restrict__ yv, const float* __restrict__ sisr,
    const double* __restrict__ k1p, const double* __restrict__ smfsp,
    const float* __restrict__ lamp, float* __restrict__ out_loss, float* __restrict__ out_lam) {
  __shared__ double red[256];
  int t = threadIdx.x;
  auto dotv = [&](const float* a, const float* b) -> double {
    double acc = 0.0;
    for (int k = t; k < N; k += 256) acc += (double)a[k] * (b ? (double)b[k] : 1.0);
    red[t] = acc; __syncthreads();
    for (int off = 128; off; off >>= 1) { if (t < off) red[t] += red[t + off]; __syncthreads(); }
    double r = red[0]; __syncthreads();
    return r;
  };
  double paas = dotv(paf, as_);
  double pbbs = dotv(pbf, bs_);
  double r1as = dotv(r1sq, as_);
  double c2bs = dotv(r2sq, bs_);
  double rs1y = dotv(rs1, yv);
  double sis  = dotv(sisr, nullptr);
  double sr1  = dotv(r1sq, nullptr);
  double sr2  = dotv(r2sq, nullptr);
  double ss1  = dotv(rs1, nullptr);
  double ss2  = dotv(rs2, nullptr);
  if (t == 0) {
    double k1 = *k1p, smfs = *smfsp;
    double lam0 = (double)*lamp;
    double k2 = 2048.0 * r1as + 2048.0 * c2bs - 2.0 * rs1y;
    double k3 = 2048.0 * 2048.0 * (sr1 + sr2) - 2.0 * ss1 * ss2;
    double upd = (k1 + 40.0 * k2) / (40.0 * k3);
    double lamn = 0.01 * upd + 0.99 * lam0;
    double g1 = paas + pbbs - 2.0 * smfs;
    double wl = sis - lamn * k1;
    double gwl = g1 - 2.0 * lamn * k2 + lamn * lamn * k3;
    double loss = wl + 20.0 * gwl + 20.0;
    *out_loss = (float)loss;
    *out_lam = (float)lamn;
  }
}

__global__ __launch_bounds__(256) void k_copys(const float* __restrict__ s, float* __restrict__ out) {
  size_t base = ((size_t)blockIdx.x * 256 + threadIdx.x) * 4;
  if (base < (size_t)N * N) {
    float4 v = *(const float4*)&s[base];
    out[base + 0] = v.x; out[base + 1] = v.y; out[base + 2] = v.z; out[base + 3] = v.w;
  }
}

// ---------------------------------------------------------------- launch

extern "C" void kernel_launch(void* const* d_in, const int* in_sizes, int n_in,
                              void* d_out, int out_size, void* d_ws, size_t ws_size,
                              hipStream_t stream) {
  (void)in_sizes; (void)n_in; (void)out_size; (void)ws_size;
  const float* out1 = (const float*)d_in[0];
  const float* out2 = (const float*)d_in[1];
  const float* adj1 = (const float*)d_in[2];
  const float* adj2 = (const float*)d_in[3];
  const float* lamp = (const float*)d_in[4];
  float* o = (float*)d_out;

  char* w = (char*)d_ws;
  size_t off = 0;
  auto alloc = [&](size_t bytes) -> void* {
    void* p = w + off;
    off = (off + bytes + 255) & ~(size_t)255;
    return p;
  };
  const size_t NNf = (size_t)N * N * sizeof(float);
  float* inter = (float*)alloc(NNf);
  float* Ttbuf = (float*)alloc(NNf);
  float* Mbuf  = (float*)alloc(NNf);
  float* sbuf  = (float*)alloc(NNf);
  int* rp1   = (int*)alloc((N + 1) * sizeof(int));
  int* rp2   = (int*)alloc((N + 1) * sizeof(int));
  int* cnt   = (int*)alloc(N * sizeof(int));
  int* cols1 = (int*)alloc(CAP * sizeof(int));
  int* rows1 = (int*)alloc(CAP * sizeof(int));
  int* cols2 = (int*)alloc(CAP * sizeof(int));
  int* rows2 = (int*)alloc(CAP * sizeof(int));
  float* vals1 = (float*)alloc(CAP * sizeof(float));
  float* vals2 = (float*)alloc(CAP * sizeof(float));
  float* r1sq = (float*)alloc(N * sizeof(float));
  float* rs1  = (float*)alloc(N * sizeof(float));
  float* r2sq = (float*)alloc(N * sizeof(float));
  float* rs2v = (float*)alloc(N * sizeof(float));
  float* asv  = (float*)alloc(N * sizeof(float));
  float* bsv  = (float*)alloc(N * sizeof(float));
  float* vglob= (float*)alloc(N * sizeof(float));
  float* Ai   = (float*)alloc(N * sizeof(float));
  float* Bj   = (float*)alloc(N * sizeof(float));
  float* RLi  = (float*)alloc(N * sizeof(float));
  float* yv   = (float*)alloc(N * sizeof(float));
  float* sisr = (float*)alloc(N * sizeof(float));
  float* paf  = (float*)alloc(N * sizeof(float));
  float* pbf  = (float*)alloc(N * sizeof(float));
  float* part = (float*)alloc((size_t)512 * N * sizeof(float));
  float* bsp  = (float*)alloc((size_t)512 * N * sizeof(float));
  double* k1acc = (double*)alloc(sizeof(double));
  double* smfs  = (double*)alloc(sizeof(double));

  dim3 b(256);

  // ---- precompute
  k_init<<<1, b, 0, stream>>>(k1acc, smfs);
  k_gemm_inter<<<dim3(32, 32), b, 0, stream>>>(out1, out2, inter, k1acc);
  k_count<<<512, b, 0, stream>>>(adj1, cnt);
  k_scan<<<1, b, 0, stream>>>(cnt, rp1);
  k_count<<<512, b, 0, stream>>>(adj2, cnt);
  k_scan<<<1, b, 0, stream>>>(cnt, rp2);
  k_fill<<<512, b, 0, stream>>>(adj1, rp1, cols1, rows1);
  k_fill<<<512, b, 0, stream>>>(adj2, rp2, cols2, rows2);
  k_vals<<<CAP / 4, b, 0, stream>>>(rp1, rows1, cols1, vals1, out1);
  k_vals<<<CAP / 4, b, 0, stream>>>(rp2, rows2, cols2, vals2, out2);
  k_rowstats<<<512, b, 0, stream>>>(rp1, vals1, rs1, r1sq);
  k_rowstats<<<512, b, 0, stream>>>(rp2, vals2, rs2v, r2sq);

  // ---- cooperative outer iterations
  int hasM = 0;
  void* cargs[] = {
    (void*)&inter, (void*)&Mbuf, (void*)&sbuf,
    (void*)&rp1, (void*)&cols1, (void*)&vals1,
    (void*)&rp2, (void*)&cols2, (void*)&vals2,
    (void*)&r1sq, (void*)&rs1, (void*)&r2sq, (void*)&rs2v,
    (void*)&asv, (void*)&bsv, (void*)&lamp,
    (void*)&Ai, (void*)&Bj, (void*)&RLi,
    (void*)&vglob, (void*)&part, (void*)&bsp, (void*)&hasM
  };
  for (int t = 0; t < 10; ++t) {
    if (t > 0) {
      k_spmmt<<<2048, b, 0, stream>>>(rp1, cols1, vals1, sbuf, Ttbuf);
      k_spmmt<<<2048, b, 0, stream>>>(rp2, cols2, vals2, Ttbuf, Mbuf);
    }
    hasM = (t > 0) ? 1 : 0;
    hipLaunchCooperativeKernel((void*)k_coop, dim3(512), b, cargs, 0, stream);
  }

  // ---- final: lambda update + loss
  k_spmmt<<<2048, b, 0, stream>>>(rp1, cols1, vals1, sbuf, Ttbuf);
  k_spmmt<<<2048, b, 0, stream>>>(rp2, cols2, vals2, Ttbuf, Mbuf);
  k_prep2<<<16, b, 0, stream>>>(rp1, cols1, vals1, rp2, cols2, vals2, asv, bsv, paf, pbf);
  k_rowdots<<<512, b, 0, stream>>>(inter, sbuf, rs2v, sisr, yv);
  k_dotMS<<<4096, b, 0, stream>>>(Mbuf, sbuf, smfs);
  k_final<<<1, b, 0, stream>>>(paf, pbf, r1sq, r2sq, rs1, rs2v, asv, bsv, yv, sisr,
                               k1acc, smfs, lamp, o, o + 1 + (size_t)N * N);
  k_copys<<<4096, b, 0, stream>>>(sbuf, o + 1);
}

// Round 5
// 1674.687 us; speedup vs baseline: 5.3077x; 5.3077x over previous
//
#include <hip/hip_runtime.h>
#include <math.h>

#define N 2048
#define DIM 128
#define CAP (N*64)
#define LOGN 7.6246189861593985f

typedef unsigned long long u64;
typedef unsigned int u32;

// ---------------------------------------------------------------- precompute

__global__ __launch_bounds__(256) void k_init(double* k1acc, double* smfs) {
  if (threadIdx.x == 0) { *k1acc = 0.0; *smfs = 0.0; }
}

// inter = exp(-(A @ B^T)), accumulate k1 = sum(inter)
__global__ __launch_bounds__(256) void k_gemm_inter(
    const float* __restrict__ A, const float* __restrict__ B,
    float* __restrict__ O, double* __restrict__ k1acc) {
  __shared__ __align__(16) float As[64][65];
  __shared__ __align__(16) float Bs[64][65];
  __shared__ float red[256];
  const int t = threadIdx.x;
  const int i0 = blockIdx.y * 64, j0 = blockIdx.x * 64;
  const int tx = t & 15, ty = t >> 4;
  float acc[4][4] = {};
  for (int kk = 0; kk < DIM; kk += 64) {
    if (kk) __syncthreads();
    for (int q = t; q < 64 * 16; q += 256) {
      int row = q >> 4, k4 = (q & 15) << 2;
      float4 av = *(const float4*)&A[(size_t)(i0 + row) * DIM + kk + k4];
      As[k4 + 0][row] = av.x; As[k4 + 1][row] = av.y;
      As[k4 + 2][row] = av.z; As[k4 + 3][row] = av.w;
      float4 bv = *(const float4*)&B[(size_t)(j0 + row) * DIM + kk + k4];
      Bs[k4 + 0][row] = bv.x; Bs[k4 + 1][row] = bv.y;
      Bs[k4 + 2][row] = bv.z; Bs[k4 + 3][row] = bv.w;
    }
    __syncthreads();
    #pragma unroll 4
    for (int k = 0; k < 64; ++k) {
      float av[4], bv[4];
      #pragma unroll
      for (int d = 0; d < 4; ++d) { av[d] = As[k][ty * 4 + d]; bv[d] = Bs[k][tx * 4 + d]; }
      #pragma unroll
      for (int di = 0; di < 4; ++di)
        #pragma unroll
        for (int dj = 0; dj < 4; ++dj)
          acc[di][dj] = fmaf(av[di], bv[dj], acc[di][dj]);
    }
  }
  float psum = 0.f;
  #pragma unroll
  for (int di = 0; di < 4; ++di)
    #pragma unroll
    for (int dj = 0; dj < 4; ++dj) {
      float vv = __expf(-acc[di][dj]);
      O[(size_t)(i0 + ty * 4 + di) * N + (j0 + tx * 4 + dj)] = vv;
      psum += vv;
    }
  red[t] = psum; __syncthreads();
  for (int off = 128; off; off >>= 1) { if (t < off) red[t] += red[t + off]; __syncthreads(); }
  if (t == 0) atomicAdd(k1acc, (double)red[0]);
}

__global__ __launch_bounds__(256) void k_count(const float* __restrict__ adj, int* __restrict__ cnt) {
  int i = blockIdx.x * 4 + (threadIdx.x >> 6);
  int lane = threadIdx.x & 63;
  const float* row = adj + (size_t)i * N;
  int c = 0;
  for (int j = lane; j < N; j += 64) c += (row[j] != 0.f) ? 1 : 0;
  for (int off = 32; off; off >>= 1) c += __shfl_down(c, off);
  if (lane == 0) cnt[i] = c;
}

__global__ __launch_bounds__(256) void k_scan(const int* __restrict__ cnt, int* __restrict__ rp) {
  __shared__ int sums[256];
  int t = threadIdx.x;
  int local[8]; int run = 0;
  int base = t * 8;
  #pragma unroll
  for (int k = 0; k < 8; ++k) { local[k] = run; run += cnt[base + k]; }
  sums[t] = run; __syncthreads();
  for (int off = 1; off < 256; off <<= 1) {
    int val = (t >= off) ? sums[t - off] : 0;
    __syncthreads();
    sums[t] += val;
    __syncthreads();
  }
  int pre = (t == 0) ? 0 : sums[t - 1];
  #pragma unroll
  for (int k = 0; k < 8; ++k) rp[base + k] = pre + local[k];
  if (t == 255) rp[N] = sums[255];
}

__global__ __launch_bounds__(256) void k_fill(const float* __restrict__ adj, const int* __restrict__ rp,
                                              int* __restrict__ cols, int* __restrict__ rows) {
  int i = blockIdx.x * 4 + (threadIdx.x >> 6);
  int lane = threadIdx.x & 63;
  const float* row = adj + (size_t)i * N;
  int pos = rp[i];
  for (int j0 = 0; j0 < N; j0 += 64) {
    bool p = row[j0 + lane] != 0.f;
    u64 mask = __ballot(p);
    if (p) {
      int off = __popcll(mask & ((1ull << lane) - 1ull));
      cols[pos + off] = j0 + lane;
      rows[pos + off] = i;
    }
    pos += __popcll(mask);
  }
}

// vals[p] = exp(-dot(emb[rows[p]], emb[cols[p]]))
__global__ __launch_bounds__(256) void k_vals(const int* __restrict__ rp, const int* __restrict__ rows,
                                              const int* __restrict__ cols, float* __restrict__ vals,
                                              const float* __restrict__ emb) {
  int p = blockIdx.x * 4 + (threadIdx.x >> 6);
  int lane = threadIdx.x & 63;
  int total = rp[N];
  if (p >= total) return;
  int i = rows[p], k = cols[p];
  const float* ei = emb + (size_t)i * DIM;
  const float* ek = emb + (size_t)k * DIM;
  float s = ei[lane] * ek[lane] + ei[lane + 64] * ek[lane + 64];
  for (int off = 32; off; off >>= 1) s += __shfl_down(s, off);
  if (lane == 0) vals[p] = __expf(-s);
}

__global__ __launch_bounds__(256) void k_rowstats(const int* __restrict__ rp, const float* __restrict__ vals,
                                                  float* __restrict__ rs, float* __restrict__ rsq) {
  int i = blockIdx.x * 4 + (threadIdx.x >> 6);
  int lane = threadIdx.x & 63;
  int p0 = rp[i], p1 = rp[i + 1];
  float s1 = 0.f, s2 = 0.f;
  for (int p = p0 + lane; p < p1; p += 64) { float w = vals[p]; s1 += w; s2 += w * w; }
  for (int off = 32; off; off >>= 1) { s1 += __shfl_down(s1, off); s2 += __shfl_down(s2, off); }
  if (lane == 0) { rs[i] = s1; rsq[i] = s2; }
}

// ---------------------------------------------------------------- spmm
// Out = (csr @ S)^T. CSR window (8 rows) staged in LDS, cols pre-*N.
// One column per thread; thread's 8 results = contiguous output row segment.
// tile = bid&7 pins the 256-col S slice to one XCD's L2.
__global__ __launch_bounds__(256) void k_spmmt(const int* __restrict__ rp, const int* __restrict__ cols,
                                               const float* __restrict__ vals, const float* __restrict__ S,
                                               float* __restrict__ Out) {
  __shared__ int winc[1024];
  __shared__ float winv[1024];
  __shared__ int rb[9];
  const int t = threadIdx.x;
  const int tile = blockIdx.x & 7;
  const int c = tile * 256 + t;
  const int i0 = (blockIdx.x >> 3) * 8;
  const int p0 = rp[i0];
  if (t < 9) rb[t] = rp[i0 + t] - p0;
  __syncthreads();
  const int nn = rb[8];
  for (int k = t; k < nn; k += 256) {
    winc[k] = cols[p0 + k] << 11;     // *N
    winv[k] = vals[p0 + k];
  }
  __syncthreads();
  float a[8];
  #pragma unroll
  for (int r = 0; r < 8; ++r) {
    int pe = rb[r + 1];
    int p = rb[r];
    float a0 = 0.f, a1 = 0.f, a2 = 0.f, a3 = 0.f;
    for (; p + 3 < pe; p += 4) {
      a0 = fmaf(winv[p],     S[winc[p]     + c], a0);
      a1 = fmaf(winv[p + 1], S[winc[p + 1] + c], a1);
      a2 = fmaf(winv[p + 2], S[winc[p + 2] + c], a2);
      a3 = fmaf(winv[p + 3], S[winc[p + 3] + c], a3);
    }
    for (; p < pe; ++p) a0 = fmaf(winv[p], S[winc[p] + c], a0);
    a[r] = (a0 + a1) + (a2 + a3);
  }
  size_t ob = (size_t)(tile * 256 + t) * N + i0;
  *(float4*)&Out[ob]     = make_float4(a[0], a[1], a[2], a[3]);
  *(float4*)&Out[ob + 4] = make_float4(a[4], a[5], a[6], a[7]);
}

// ---------------------------------------------------------------- prep
// mode 0: t==0 analytic (s uniform);  mode 1: general;  mode 2: final raw pa/pb
__global__ __launch_bounds__(256) void k_prep(
    int mode,
    const int* __restrict__ rp1, const int* __restrict__ cols1, const float* __restrict__ vals1,
    const int* __restrict__ rp2, const int* __restrict__ cols2, const float* __restrict__ vals2,
    const float* __restrict__ r1sq, const float* __restrict__ rs1,
    const float* __restrict__ r2sq, const float* __restrict__ rs2,
    const float* __restrict__ as_, const float* __restrict__ bs_,
    const float* __restrict__ lamp,
    float* __restrict__ Ai, float* __restrict__ Bj, float* __restrict__ RLi,
    float* __restrict__ v) {
  int g = blockIdx.x * 256 + threadIdx.x;
  float lam = *lamp;
  if (mode == 0) {
    float f = 0.00048828125f - lam * 2048.f;            // 2048*(s0 - lam)
    if (g < N) {
      Ai[g] = -2000.f * r1sq[g] * f;
      RLi[g] = 4000.f * rs1[g] * (2.384185791015625e-07f - lam);
    } else if (g < 2 * N) {
      int j = g - N;
      Bj[j] = -2000.f * r2sq[j] * f;
    } else if (g < 3 * N) {
      v[g - 2 * N] = 0.f;
    }
  } else if (mode == 1) {
    if (g < N) {
      int p0 = rp1[g], p1 = rp1[g + 1];
      float acc = 0.f;
      for (int p = p0; p < p1; ++p) { float w = vals1[p]; acc = fmaf(w * w, as_[cols1[p]], acc); }
      Ai[g] = -2000.f * (acc - lam * 2048.f * r1sq[g]);
      RLi[g] = -4000.f * lam * rs1[g];
    } else if (g < 2 * N) {
      int j = g - N;
      int p0 = rp2[j], p1 = rp2[j + 1];
      float acc = 0.f;
      for (int p = p0; p < p1; ++p) { float w = vals2[p]; acc = fmaf(w * w, bs_[cols2[p]], acc); }
      Bj[j] = -2000.f * (acc - lam * 2048.f * r2sq[j]);
    } else if (g < 3 * N) {
      v[g - 2 * N] = 0.f;
    }
  } else {
    if (g < N) {
      int p0 = rp1[g], p1 = rp1[g + 1];
      float acc = 0.f;
      for (int p = p0; p < p1; ++p) { float w = vals1[p]; acc = fmaf(w * w, as_[cols1[p]], acc); }
      Ai[g] = acc;                                      // paf
    } else if (g < 2 * N) {
      int j = g - N;
      int p0 = rp2[j], p1 = rp2[j + 1];
      float acc = 0.f;
      for (int p = p0; p < p1; ++p) { float w = vals2[p]; acc = fmaf(w * w, bs_[cols2[p]], acc); }
      Bj[j] = acc;                                      // pbf
    }
  }
}

// ---------------------------------------------------------------- sinkhorn iteration
// Block owns rows r0..r0+3 of K (staged/built in LDS). Row LSE -> u; col partials -> part.
// MODE 0: read K from global. MODE 1: build K = -100*inter + Ai + Bj + RLi*rs2 + 4000*M, write K.
// MODE 2: build without M (t==0 outer).
template<int MODE>
__global__ __launch_bounds__(256) void k_sink(
    const float* __restrict__ K, float* __restrict__ Kw,
    const float* __restrict__ inter, const float* __restrict__ M,
    const float* __restrict__ Ai, const float* __restrict__ Bj,
    const float* __restrict__ RLi, const float* __restrict__ rs2,
    const float* __restrict__ vglob, float* __restrict__ u, float* __restrict__ part) {
  __shared__ __align__(16) float Ks[4 * N];
  __shared__ __align__(16) float vs[N];
  __shared__ float us4[4], aih[4], rlih[4];
  const int t = threadIdx.x;
  const int r0 = blockIdx.x * 4;
  #pragma unroll
  for (int q = 0; q < 2; ++q) {
    int j = (q * 256 + t) * 4;
    *(float4*)&vs[j] = *(const float4*)&vglob[j];
  }
  if (MODE != 0) {
    if (t < 4) { aih[t] = Ai[r0 + t]; rlih[t] = RLi[r0 + t]; }
    __syncthreads();
    #pragma unroll 2
    for (int q = 0; q < 8; ++q) {
      int j = q * 256 + t;
      float bv = Bj[j], r2 = rs2[j];
      #pragma unroll
      for (int r = 0; r < 4; ++r) {
        size_t idx = (size_t)(r0 + r) * N + j;
        float kv = fmaf(-100.f, inter[idx], aih[r] + bv + rlih[r] * r2);
        if (MODE == 1) kv = fmaf(4000.f, M[idx], kv);
        Ks[r * N + j] = kv;
        Kw[idx] = kv;
      }
    }
  } else {
    #pragma unroll
    for (int q = 0; q < 8; ++q) {
      int lin = (q * 256 + t) * 4;
      *(float4*)&Ks[lin] = *(const float4*)&K[(size_t)r0 * N + lin];
    }
  }
  __syncthreads();
  const int w = t >> 6, lane = t & 63;
  // row LSE: wave w owns row w
  {
    float m = -INFINITY, ss = 0.f;
    const float* Kr = Ks + w * N;
    #pragma unroll
    for (int q = 0; q < 8; ++q) {
      int j = lane * 4 + q * 256;
      float4 kv = *(const float4*)&Kr[j];
      float x0 = kv.x + vs[j], x1 = kv.y + vs[j + 1];
      float x2 = kv.z + vs[j + 2], x3 = kv.w + vs[j + 3];
      float mx = fmaxf(fmaxf(x0, x1), fmaxf(x2, x3));
      float nm = fmaxf(m, mx);
      ss = ss * __expf(m - nm) + __expf(x0 - nm) + __expf(x1 - nm)
                               + __expf(x2 - nm) + __expf(x3 - nm);
      m = nm;
    }
    for (int off = 32; off; off >>= 1) {
      float mo = __shfl_xor(m, off), so = __shfl_xor(ss, off);
      float nm = fmaxf(m, mo);
      ss = ss * __expf(m - nm) + so * __expf(mo - nm);
      m = nm;
    }
    float uw = -LOGN - (m + __logf(ss));
    if (lane == 0) { us4[w] = uw; u[r0 + w] = uw; }
  }
  __syncthreads();
  // col partials over own 4 rows
  {
    float u0 = us4[0], u1 = us4[1], u2 = us4[2], u3 = us4[3];
    #pragma unroll 2
    for (int q = 0; q < 8; ++q) {
      int c = q * 256 + t;
      float x0 = Ks[c] + u0, x1 = Ks[N + c] + u1;
      float x2 = Ks[2 * N + c] + u2, x3 = Ks[3 * N + c] + u3;
      float m = fmaxf(fmaxf(x0, x1), fmaxf(x2, x3));
      float ss = __expf(x0 - m) + __expf(x1 - m) + __expf(x2 - m) + __expf(x3 - m);
      part[(size_t)blockIdx.x * N + c] = m + __logf(ss);
    }
  }
}

// combine 512 per-stripe partial LSEs -> v  (64 blocks x 32 cols, 8 k-groups/col)
__global__ __launch_bounds__(256) void k_comb(const float* __restrict__ part, float* __restrict__ v) {
  __shared__ float pp[8][33];
  const int t = threadIdx.x;
  const int cl = t & 31, kk = t >> 5;
  const int c = blockIdx.x * 32 + cl;
  float m = -INFINITY, s = 0.f;
  for (int k = kk * 64; k < kk * 64 + 64; ++k) {
    float x = part[(size_t)k * N + c];
    float nm = fmaxf(m, x);
    s = s * __expf(m - nm) + __expf(x - nm);
    m = nm;
  }
  pp[kk][cl] = m + __logf(s);
  __syncthreads();
  if (t < 32) {
    float m2 = -INFINITY, s2 = 0.f;
    #pragma unroll
    for (int g = 0; g < 8; ++g) {
      float x = pp[g][t];
      float nm = fmaxf(m2, x);
      s2 = s2 * __expf(m2 - nm) + __expf(x - nm);
      m2 = nm;
    }
    v[blockIdx.x * 32 + t] = -LOGN - (m2 + __logf(s2));
  }
}

// s = exp(K + u + v); rowsums -> as_, per-block column partials -> bsp; optional copy to s2
__global__ __launch_bounds__(256) void k_swrite(const float* __restrict__ K, const float* __restrict__ u,
                                                const float* __restrict__ v, float* __restrict__ s,
                                                float* __restrict__ as_, float* __restrict__ bsp,
                                                float* __restrict__ s2) {
  __shared__ __align__(16) float vs[N];
  __shared__ __align__(16) float bc[N];
  int t = threadIdx.x;
  for (int j = t * 4; j < N; j += 1024) *(float4*)&vs[j] = *(const float4*)&v[j];
  __syncthreads();
  int lane = t & 63, w = t >> 6;
  float4 cacc[8];
  #pragma unroll
  for (int q = 0; q < 8; ++q) cacc[q] = make_float4(0.f, 0.f, 0.f, 0.f);
  int ibase = blockIdx.x * 8 + w * 2;
  for (int rr = 0; rr < 2; ++rr) {
    int i = ibase + rr;
    float ui = u[i];
    const float* Kr = K + (size_t)i * N;
    float* sr = s + (size_t)i * N;
    float rsum = 0.f;
    #pragma unroll
    for (int q = 0; q < 8; ++q) {
      int j = lane * 4 + q * 256;
      float4 kv = *(const float4*)&Kr[j];
      float4 sv;
      sv.x = __expf(kv.x + ui + vs[j]);
      sv.y = __expf(kv.y + ui + vs[j + 1]);
      sv.z = __expf(kv.z + ui + vs[j + 2]);
      sv.w = __expf(kv.w + ui + vs[j + 3]);
      *(float4*)&sr[j] = sv;
      if (s2) *(float4*)&s2[(size_t)i * N + j] = sv;
      rsum += sv.x + sv.y + sv.z + sv.w;
      cacc[q].x += sv.x; cacc[q].y += sv.y; cacc[q].z += sv.z; cacc[q].w += sv.w;
    }
    for (int off = 32; off; off >>= 1) rsum += __shfl_down(rsum, off);
    if (lane == 0) as_[i] = rsum;
  }
  for (int ww = 0; ww < 4; ++ww) {
    if (w == ww) {
      #pragma unroll
      for (int q = 0; q < 8; ++q) {
        int j = lane * 4 + q * 256;
        if (ww == 0) *(float4*)&bc[j] = cacc[q];
        else {
          float4 old = *(float4*)&bc[j];
          old.x += cacc[q].x; old.y += cacc[q].y; old.z += cacc[q].z; old.w += cacc[q].w;
          *(float4*)&bc[j] = old;
        }
      }
    }
    __syncthreads();
  }
  float* bout = bsp + (size_t)blockIdx.x * N;
  for (int j = t * 4; j < N; j += 1024) *(float4*)&bout[j] = *(const float4*)&bc[j];
}

__global__ __launch_bounds__(256) void k_bscomb(const float* __restrict__ bsp, float* __restrict__ bs_) {
  int c = blockIdx.x * 256 + threadIdx.x;
  float acc = 0.f;
  for (int b = 0; b < 256; ++b) acc += bsp[(size_t)b * N + c];
  bs_[c] = acc;
}

// ---------------------------------------------------------------- final

__global__ __launch_bounds__(256) void k_rowdots(const float* __restrict__ inter, const float* __restrict__ s,
                                                 const float* __restrict__ rs2, float* __restrict__ sisr,
                                                 float* __restrict__ yv) {
  __shared__ __align__(16) float r2[N];
  int t = threadIdx.x;
  for (int j = t * 4; j < N; j += 1024) *(float4*)&r2[j] = *(const float4*)&rs2[j];
  __syncthreads();
  int lane = t & 63;
  int i = blockIdx.x * 4 + (t >> 6);
  const float* ir = inter + (size_t)i * N;
  const float* sr = s + (size_t)i * N;
  float d1 = 0.f, d2 = 0.f;
  for (int j = lane * 4; j < N; j += 256) {
    float4 iv = *(const float4*)&ir[j];
    float4 sv = *(const float4*)&sr[j];
    d1 += iv.x * sv.x + iv.y * sv.y + iv.z * sv.z + iv.w * sv.w;
    d2 += sv.x * r2[j] + sv.y * r2[j + 1] + sv.z * r2[j + 2] + sv.w * r2[j + 3];
  }
  for (int off = 32; off; off >>= 1) { d1 += __shfl_down(d1, off); d2 += __shfl_down(d2, off); }
  if (lane == 0) { sisr[i] = d1; yv[i] = d2; }
}

// smfs += sum(M .* s), both row-major
__global__ __launch_bounds__(256) void k_dotMS(const float* __restrict__ M, const float* __restrict__ s,
                                               double* __restrict__ acc) {
  __shared__ double red[256];
  int t = threadIdx.x;
  size_t base = ((size_t)blockIdx.x * 256 + t) * 4;
  float4 mv = *(const float4*)&M[base];
  float4 sv = *(const float4*)&s[base];
  double a = (double)(mv.x * sv.x) + (double)(mv.y * sv.y)
           + (double)(mv.z * sv.z) + (double)(mv.w * sv.w);
  red[t] = a; __syncthreads();
  for (int off = 128; off; off >>= 1) { if (t < off) red[t] += red[t + off]; __syncthreads(); }
  if (t == 0) atomicAdd(acc, red[0]);
}

__global__ __launch_bounds__(256) void k_final(
    const float* __restrict__ paf, const float* __restrict__ pbf,
    const float* __restrict__ r1sq, const float* __restrict__ r2sq,
    const float* __restrict__ rs1, const float* __restrict__ rs2,
    const float* __restrict__ as_, const float* __restrict__ bs_,
    const float* __restrict__ yv, const float* __restrict__ sisr,
    const double* __restrict__ k1p, const double* __restrict__ smfsp,
    const float* __restrict__ lamp, float* __restrict__ out_loss, float* __restrict__ out_lam) {
  __shared__ double red[256];
  int t = threadIdx.x;
  auto dotv = [&](const float* a, const float* b) -> double {
    double acc = 0.0;
    for (int k = t; k < N; k += 256) acc += (double)a[k] * (b ? (double)b[k] : 1.0);
    red[t] = acc; __syncthreads();
    for (int off = 128; off; off >>= 1) { if (t < off) red[t] += red[t + off]; __syncthreads(); }
    double r = red[0]; __syncthreads();
    return r;
  };
  double paas = dotv(paf, as_);
  double pbbs = dotv(pbf, bs_);
  double r1as = dotv(r1sq, as_);
  double c2bs = dotv(r2sq, bs_);
  double rs1y = dotv(rs1, yv);
  double sis  = dotv(sisr, nullptr);
  double sr1  = dotv(r1sq, nullptr);
  double sr2  = dotv(r2sq, nullptr);
  double ss1  = dotv(rs1, nullptr);
  double ss2  = dotv(rs2, nullptr);
  if (t == 0) {
    double k1 = *k1p, smfs = *smfsp;
    double lam0 = (double)*lamp;
    double k2 = 2048.0 * r1as + 2048.0 * c2bs - 2.0 * rs1y;
    double k3 = 2048.0 * 2048.0 * (sr1 + sr2) - 2.0 * ss1 * ss2;
    double upd = (k1 + 40.0 * k2) / (40.0 * k3);
    double lamn = 0.01 * upd + 0.99 * lam0;
    double g1 = paas + pbbs - 2.0 * smfs;
    double wl = sis - lamn * k1;
    double gwl = g1 - 2.0 * lamn * k2 + lamn * lamn * k3;
    double loss = wl + 20.0 * gwl + 20.0;
    *out_loss = (float)loss;
    *out_lam = (float)lamn;
  }
}

// ---------------------------------------------------------------- launch

extern "C" void kernel_launch(void* const* d_in, const int* in_sizes, int n_in,
                              void* d_out, int out_size, void* d_ws, size_t ws_size,
                              hipStream_t stream) {
  (void)in_sizes; (void)n_in; (void)out_size; (void)ws_size;
  const float* out1 = (const float*)d_in[0];
  const float* out2 = (const float*)d_in[1];
  const float* adj1 = (const float*)d_in[2];
  const float* adj2 = (const float*)d_in[3];
  const float* lamp = (const float*)d_in[4];
  float* o = (float*)d_out;

  char* w = (char*)d_ws;
  size_t off = 0;
  auto alloc = [&](size_t bytes) -> void* {
    void* p = w + off;
    off = (off + bytes + 255) & ~(size_t)255;
    return p;
  };
  const size_t NNf = (size_t)N * N * sizeof(float);
  float* inter = (float*)alloc(NNf);
  float* Ttbuf = (float*)alloc(NNf);
  float* Mbuf  = (float*)alloc(NNf);
  float* Kbuf  = (float*)alloc(NNf);
  float* sbuf  = (float*)alloc(NNf);
  int* rp1   = (int*)alloc((N + 1) * sizeof(int));
  int* rp2   = (int*)alloc((N + 1) * sizeof(int));
  int* cnt   = (int*)alloc(N * sizeof(int));
  int* cols1 = (int*)alloc(CAP * sizeof(int));
  int* rows1 = (int*)alloc(CAP * sizeof(int));
  int* cols2 = (int*)alloc(CAP * sizeof(int));
  int* rows2 = (int*)alloc(CAP * sizeof(int));
  float* vals1 = (float*)alloc(CAP * sizeof(float));
  float* vals2 = (float*)alloc(CAP * sizeof(float));
  float* r1sq = (float*)alloc(N * sizeof(float));
  float* rs1  = (float*)alloc(N * sizeof(float));
  float* r2sq = (float*)alloc(N * sizeof(float));
  float* rs2v = (float*)alloc(N * sizeof(float));
  float* asv  = (float*)alloc(N * sizeof(float));
  float* bsv  = (float*)alloc(N * sizeof(float));
  float* uv   = (float*)alloc(N * sizeof(float));
  float* vv   = (float*)alloc(N * sizeof(float));
  float* Ai   = (float*)alloc(N * sizeof(float));
  float* Bj   = (float*)alloc(N * sizeof(float));
  float* RLi  = (float*)alloc(N * sizeof(float));
  float* yv   = (float*)alloc(N * sizeof(float));
  float* sisr = (float*)alloc(N * sizeof(float));
  float* part = (float*)alloc((size_t)512 * N * sizeof(float));
  float* bsp  = (float*)alloc((size_t)256 * N * sizeof(float));
  double* k1acc = (double*)alloc(sizeof(double));
  double* smfs  = (double*)alloc(sizeof(double));

  dim3 b(256);

  // ---- precompute
  k_init<<<1, b, 0, stream>>>(k1acc, smfs);
  k_gemm_inter<<<dim3(32, 32), b, 0, stream>>>(out1, out2, inter, k1acc);
  k_count<<<512, b, 0, stream>>>(adj1, cnt);
  k_scan<<<1, b, 0, stream>>>(cnt, rp1);
  k_count<<<512, b, 0, stream>>>(adj2, cnt);
  k_scan<<<1, b, 0, stream>>>(cnt, rp2);
  k_fill<<<512, b, 0, stream>>>(adj1, rp1, cols1, rows1);
  k_fill<<<512, b, 0, stream>>>(adj2, rp2, cols2, rows2);
  k_vals<<<CAP / 4, b, 0, stream>>>(rp1, rows1, cols1, vals1, out1);
  k_vals<<<CAP / 4, b, 0, stream>>>(rp2, rows2, cols2, vals2, out2);
  k_rowstats<<<512, b, 0, stream>>>(rp1, vals1, rs1, r1sq);
  k_rowstats<<<512, b, 0, stream>>>(rp2, vals2, rs2v, r2sq);

  // ---- outer loop
  for (int t = 0; t < 10; ++t) {
    k_prep<<<24, b, 0, stream>>>((t == 0) ? 0 : 1, rp1, cols1, vals1, rp2, cols2, vals2,
                                 r1sq, rs1, r2sq, rs2v, asv, bsv, lamp, Ai, Bj, RLi, vv);
    if (t > 0) {
      k_spmmt<<<2048, b, 0, stream>>>(rp1, cols1, vals1, sbuf, Ttbuf);
      k_spmmt<<<2048, b, 0, stream>>>(rp2, cols2, vals2, Ttbuf, Mbuf);
      k_sink<1><<<512, b, 0, stream>>>(Kbuf, Kbuf, inter, Mbuf, Ai, Bj, RLi, rs2v, vv, uv, part);
    } else {
      k_sink<2><<<512, b, 0, stream>>>(Kbuf, Kbuf, inter, Mbuf, Ai, Bj, RLi, rs2v, vv, uv, part);
    }
    k_comb<<<64, b, 0, stream>>>(part, vv);
    for (int r = 1; r < 5; ++r) {
      k_sink<0><<<512, b, 0, stream>>>(Kbuf, Kbuf, inter, Mbuf, Ai, Bj, RLi, rs2v, vv, uv, part);
      k_comb<<<64, b, 0, stream>>>(part, vv);
    }
    k_swrite<<<256, b, 0, stream>>>(Kbuf, uv, vv, sbuf, asv, bsp, (t == 9) ? (o + 1) : nullptr);
    k_bscomb<<<8, b, 0, stream>>>(bsp, bsv);
  }

  // ---- final: lambda update + loss
  k_spmmt<<<2048, b, 0, stream>>>(rp1, cols1, vals1, sbuf, Ttbuf);
  k_spmmt<<<2048, b, 0, stream>>>(rp2, cols2, vals2, Ttbuf, Mbuf);
  k_prep<<<24, b, 0, stream>>>(2, rp1, cols1, vals1, rp2, cols2, vals2,
                               r1sq, rs1, r2sq, rs2v, asv, bsv, lamp, Ai, Bj, RLi, vv);
  k_rowdots<<<512, b, 0, stream>>>(inter, sbuf, rs2v, sisr, yv);
  k_dotMS<<<4096, b, 0, stream>>>(Mbuf, sbuf, smfs);
  k_final<<<1, b, 0, stream>>>(Ai, Bj, r1sq, r2sq, rs1, rs2v, asv, bsv, yv, sisr,
                               k1acc, smfs, lamp, o, o + 1 + (size_t)N * N);
}

// Round 6
// 1557.405 us; speedup vs baseline: 5.7074x; 1.0753x over previous
//
#include <hip/hip_runtime.h>
#include <hip/hip_fp16.h>
#include <math.h>

#define N 2048
#define DIM 128
#define CAP (N*64)
#define LOGN 7.6246189861593985f
#define SSCALE 16384.0f
#define ISCALE 6.103515625e-05f   // 1/16384

typedef unsigned long long u64;
typedef unsigned int u32;

// ---------------------------------------------------------------- precompute

// inter = exp(-(A @ B^T)); per-block partial sums -> k1p
__global__ __launch_bounds__(256) void k_gemm_inter(
    const float* __restrict__ A, const float* __restrict__ B,
    float* __restrict__ O, double* __restrict__ k1p) {
  __shared__ __align__(16) float As[64][65];
  __shared__ __align__(16) float Bs[64][65];
  __shared__ float red[256];
  const int t = threadIdx.x;
  const int i0 = blockIdx.y * 64, j0 = blockIdx.x * 64;
  const int tx = t & 15, ty = t >> 4;
  float acc[4][4] = {};
  for (int kk = 0; kk < DIM; kk += 64) {
    if (kk) __syncthreads();
    for (int q = t; q < 64 * 16; q += 256) {
      int row = q >> 4, k4 = (q & 15) << 2;
      float4 av = *(const float4*)&A[(size_t)(i0 + row) * DIM + kk + k4];
      As[k4 + 0][row] = av.x; As[k4 + 1][row] = av.y;
      As[k4 + 2][row] = av.z; As[k4 + 3][row] = av.w;
      float4 bv = *(const float4*)&B[(size_t)(j0 + row) * DIM + kk + k4];
      Bs[k4 + 0][row] = bv.x; Bs[k4 + 1][row] = bv.y;
      Bs[k4 + 2][row] = bv.z; Bs[k4 + 3][row] = bv.w;
    }
    __syncthreads();
    #pragma unroll 4
    for (int k = 0; k < 64; ++k) {
      float av[4], bv[4];
      #pragma unroll
      for (int d = 0; d < 4; ++d) { av[d] = As[k][ty * 4 + d]; bv[d] = Bs[k][tx * 4 + d]; }
      #pragma unroll
      for (int di = 0; di < 4; ++di)
        #pragma unroll
        for (int dj = 0; dj < 4; ++dj)
          acc[di][dj] = fmaf(av[di], bv[dj], acc[di][dj]);
    }
  }
  float psum = 0.f;
  #pragma unroll
  for (int di = 0; di < 4; ++di)
    #pragma unroll
    for (int dj = 0; dj < 4; ++dj) {
      float vv = __expf(-acc[di][dj]);
      O[(size_t)(i0 + ty * 4 + di) * N + (j0 + tx * 4 + dj)] = vv;
      psum += vv;
    }
  red[t] = psum; __syncthreads();
  for (int off = 128; off; off >>= 1) { if (t < off) red[t] += red[t + off]; __syncthreads(); }
  if (t == 0) k1p[blockIdx.y * 32 + blockIdx.x] = (double)red[0];
}

__global__ __launch_bounds__(256) void k_count(const float* __restrict__ adj, int* __restrict__ cnt) {
  int i = blockIdx.x * 4 + (threadIdx.x >> 6);
  int lane = threadIdx.x & 63;
  const float* row = adj + (size_t)i * N;
  int c = 0;
  for (int j = lane; j < N; j += 64) c += (row[j] != 0.f) ? 1 : 0;
  for (int off = 32; off; off >>= 1) c += __shfl_down(c, off);
  if (lane == 0) cnt[i] = c;
}

__global__ __launch_bounds__(256) void k_scan(const int* __restrict__ cnt, int* __restrict__ rp) {
  __shared__ int sums[256];
  int t = threadIdx.x;
  int local[8]; int run = 0;
  int base = t * 8;
  #pragma unroll
  for (int k = 0; k < 8; ++k) { local[k] = run; run += cnt[base + k]; }
  sums[t] = run; __syncthreads();
  for (int off = 1; off < 256; off <<= 1) {
    int val = (t >= off) ? sums[t - off] : 0;
    __syncthreads();
    sums[t] += val;
    __syncthreads();
  }
  int pre = (t == 0) ? 0 : sums[t - 1];
  #pragma unroll
  for (int k = 0; k < 8; ++k) rp[base + k] = pre + local[k];
  if (t == 255) rp[N] = sums[255];
}

__global__ __launch_bounds__(256) void k_fill(const float* __restrict__ adj, const int* __restrict__ rp,
                                              int* __restrict__ cols, int* __restrict__ rows) {
  int i = blockIdx.x * 4 + (threadIdx.x >> 6);
  int lane = threadIdx.x & 63;
  const float* row = adj + (size_t)i * N;
  int pos = rp[i];
  for (int j0 = 0; j0 < N; j0 += 64) {
    bool p = row[j0 + lane] != 0.f;
    u64 mask = __ballot(p);
    if (p) {
      int off = __popcll(mask & ((1ull << lane) - 1ull));
      cols[pos + off] = j0 + lane;
      rows[pos + off] = i;
    }
    pos += __popcll(mask);
  }
}

// vals[p] = exp(-dot(emb[rows[p]], emb[cols[p]])), grid-stride over nnz
__global__ __launch_bounds__(256) void k_vals(const int* __restrict__ rp, const int* __restrict__ rows,
                                              const int* __restrict__ cols, float* __restrict__ vals,
                                              const float* __restrict__ emb) {
  int lane = threadIdx.x & 63;
  int total = rp[N];
  for (int p = blockIdx.x * 4 + (threadIdx.x >> 6); p < total; p += 8192) {
    int i = rows[p], k = cols[p];
    const float* ei = emb + (size_t)i * DIM;
    const float* ek = emb + (size_t)k * DIM;
    float s = ei[lane] * ek[lane] + ei[lane + 64] * ek[lane + 64];
    for (int off = 32; off; off >>= 1) s += __shfl_down(s, off);
    if (lane == 0) vals[p] = __expf(-s);
  }
}

__global__ __launch_bounds__(256) void k_rowstats(const int* __restrict__ rp, const float* __restrict__ vals,
                                                  float* __restrict__ rs, float* __restrict__ rsq) {
  int i = blockIdx.x * 4 + (threadIdx.x >> 6);
  int lane = threadIdx.x & 63;
  int p0 = rp[i], p1 = rp[i + 1];
  float s1 = 0.f, s2 = 0.f;
  for (int p = p0 + lane; p < p1; p += 64) { float w = vals[p]; s1 += w; s2 += w * w; }
  for (int off = 32; off; off >>= 1) { s1 += __shfl_down(s1, off); s2 += __shfl_down(s2, off); }
  if (lane == 0) { rs[i] = s1; rsq[i] = s2; }
}

// ---------------------------------------------------------------- spmm (fp16-scaled input)
// Out = (csr @ S)^T. CSR window (8 rows) staged in LDS, cols pre-*N.
// One column per thread; thread's 8 results = contiguous output row segment.
// tile = bid&7 pins the 256-col S slice to one XCD's L2.
template<bool OUT_HALF>
__global__ __launch_bounds__(256) void k_spmmt(const int* __restrict__ rp, const int* __restrict__ cols,
                                               const float* __restrict__ vals, const __half* __restrict__ S,
                                               __half* __restrict__ OutH, float* __restrict__ OutF) {
  __shared__ int winc[1024];
  __shared__ float winv[1024];
  __shared__ int rb[9];
  const int t = threadIdx.x;
  const int tile = blockIdx.x & 7;
  const int c = tile * 256 + t;
  const int i0 = (blockIdx.x >> 3) * 8;
  const int p0 = rp[i0];
  if (t < 9) rb[t] = rp[i0 + t] - p0;
  __syncthreads();
  const int nn = rb[8];
  for (int k = t; k < nn; k += 256) {
    winc[k] = cols[p0 + k] << 11;     // *N
    winv[k] = vals[p0 + k];
  }
  __syncthreads();
  float a[8];
  #pragma unroll
  for (int r = 0; r < 8; ++r) {
    int pe = rb[r + 1];
    int p = rb[r];
    float a0 = 0.f, a1 = 0.f, a2 = 0.f, a3 = 0.f;
    for (; p + 3 < pe; p += 4) {
      a0 = fmaf(winv[p],     __half2float(S[winc[p]     + c]), a0);
      a1 = fmaf(winv[p + 1], __half2float(S[winc[p + 1] + c]), a1);
      a2 = fmaf(winv[p + 2], __half2float(S[winc[p + 2] + c]), a2);
      a3 = fmaf(winv[p + 3], __half2float(S[winc[p + 3] + c]), a3);
    }
    for (; p < pe; ++p) a0 = fmaf(winv[p], __half2float(S[winc[p] + c]), a0);
    a[r] = (a0 + a1) + (a2 + a3);
  }
  size_t ob = (size_t)(tile * 256 + t) * N + i0;
  if (OUT_HALF) {
    __half2 h0 = __halves2half2(__float2half_rn(a[0]), __float2half_rn(a[1]));
    __half2 h1 = __halves2half2(__float2half_rn(a[2]), __float2half_rn(a[3]));
    __half2 h2 = __halves2half2(__float2half_rn(a[4]), __float2half_rn(a[5]));
    __half2 h3 = __halves2half2(__float2half_rn(a[6]), __float2half_rn(a[7]));
    uint4 pk;
    pk.x = *(u32*)&h0; pk.y = *(u32*)&h1; pk.z = *(u32*)&h2; pk.w = *(u32*)&h3;
    *(uint4*)&OutH[ob] = pk;
  } else {
    *(float4*)&OutF[ob]     = make_float4(a[0], a[1], a[2], a[3]);
    *(float4*)&OutF[ob + 4] = make_float4(a[4], a[5], a[6], a[7]);
  }
}

// ---------------------------------------------------------------- prep
// mode 0: t==0 analytic (s uniform);  mode 1: general;  mode 2: final raw pa/pb
__global__ __launch_bounds__(256) void k_prep(
    int mode,
    const int* __restrict__ rp1, const int* __restrict__ cols1, const float* __restrict__ vals1,
    const int* __restrict__ rp2, const int* __restrict__ cols2, const float* __restrict__ vals2,
    const float* __restrict__ r1sq, const float* __restrict__ rs1,
    const float* __restrict__ r2sq, const float* __restrict__ rs2,
    const float* __restrict__ as_, const float* __restrict__ bs_,
    const float* __restrict__ lamp,
    float* __restrict__ Ai, float* __restrict__ Bj, float* __restrict__ RLi,
    float* __restrict__ v) {
  int g = blockIdx.x * 256 + threadIdx.x;
  float lam = *lamp;
  if (mode == 0) {
    float f = 0.00048828125f - lam * 2048.f;            // 2048*(s0 - lam)
    if (g < N) {
      Ai[g] = -2000.f * r1sq[g] * f;
      RLi[g] = 4000.f * rs1[g] * (2.384185791015625e-07f - lam);
    } else if (g < 2 * N) {
      int j = g - N;
      Bj[j] = -2000.f * r2sq[j] * f;
    } else if (g < 3 * N) {
      v[g - 2 * N] = 0.f;
    }
  } else if (mode == 1) {
    if (g < N) {
      int p0 = rp1[g], p1 = rp1[g + 1];
      float acc = 0.f;
      for (int p = p0; p < p1; ++p) { float w = vals1[p]; acc = fmaf(w * w, as_[cols1[p]], acc); }
      Ai[g] = -2000.f * (acc - lam * 2048.f * r1sq[g]);
      RLi[g] = -4000.f * lam * rs1[g];
    } else if (g < 2 * N) {
      int j = g - N;
      int p0 = rp2[j], p1 = rp2[j + 1];
      float acc = 0.f;
      for (int p = p0; p < p1; ++p) { float w = vals2[p]; acc = fmaf(w * w, bs_[cols2[p]], acc); }
      Bj[j] = -2000.f * (acc - lam * 2048.f * r2sq[j]);
    } else if (g < 3 * N) {
      v[g - 2 * N] = 0.f;
    }
  } else {
    if (g < N) {
      int p0 = rp1[g], p1 = rp1[g + 1];
      float acc = 0.f;
      for (int p = p0; p < p1; ++p) { float w = vals1[p]; acc = fmaf(w * w, as_[cols1[p]], acc); }
      Ai[g] = acc;                                      // paf
    } else if (g < 2 * N) {
      int j = g - N;
      int p0 = rp2[j], p1 = rp2[j + 1];
      float acc = 0.f;
      for (int p = p0; p < p1; ++p) { float w = vals2[p]; acc = fmaf(w * w, bs_[cols2[p]], acc); }
      Bj[j] = acc;                                      // pbf
    }
  }
}

// ---------------------------------------------------------------- sinkhorn iteration
// Block owns rows r0..r0+3 of K (staged/built in LDS). Row LSE -> u; col partials -> part.
// MODE 0: read K from global. MODE 1: build K (with scaled M) and write K. MODE 2: build without M.
template<int MODE>
__global__ __launch_bounds__(256) void k_sink(
    const float* __restrict__ K, float* __restrict__ Kw,
    const float* __restrict__ inter, const float* __restrict__ M,
    const float* __restrict__ Ai, const float* __restrict__ Bj,
    const float* __restrict__ RLi, const float* __restrict__ rs2,
    const float* __restrict__ vglob, float* __restrict__ u, float* __restrict__ part) {
  __shared__ __align__(16) float Ks[4 * N];
  __shared__ __align__(16) float vs[N];
  __shared__ float us4[4], aih[4], rlih[4];
  const int t = threadIdx.x;
  const int r0 = blockIdx.x * 4;
  #pragma unroll
  for (int q = 0; q < 2; ++q) {
    int j = (q * 256 + t) * 4;
    *(float4*)&vs[j] = *(const float4*)&vglob[j];
  }
  if (MODE != 0) {
    if (t < 4) { aih[t] = Ai[r0 + t]; rlih[t] = RLi[r0 + t]; }
    __syncthreads();
    #pragma unroll 2
    for (int q = 0; q < 8; ++q) {
      int j = q * 256 + t;
      float bv = Bj[j], r2 = rs2[j];
      #pragma unroll
      for (int r = 0; r < 4; ++r) {
        size_t idx = (size_t)(r0 + r) * N + j;
        float kv = fmaf(-100.f, inter[idx], aih[r] + bv + rlih[r] * r2);
        if (MODE == 1) kv = fmaf(0.244140625f, M[idx], kv);   // 4000/16384 * (M*2^14)
        Ks[r * N + j] = kv;
        Kw[idx] = kv;
      }
    }
  } else {
    #pragma unroll
    for (int q = 0; q < 8; ++q) {
      int lin = (q * 256 + t) * 4;
      *(float4*)&Ks[lin] = *(const float4*)&K[(size_t)r0 * N + lin];
    }
  }
  __syncthreads();
  const int w = t >> 6, lane = t & 63;
  // row LSE: wave w owns row w
  {
    float m = -INFINITY, ss = 0.f;
    const float* Kr = Ks + w * N;
    #pragma unroll
    for (int q = 0; q < 8; ++q) {
      int j = lane * 4 + q * 256;
      float4 kv = *(const float4*)&Kr[j];
      float x0 = kv.x + vs[j], x1 = kv.y + vs[j + 1];
      float x2 = kv.z + vs[j + 2], x3 = kv.w + vs[j + 3];
      float mx = fmaxf(fmaxf(x0, x1), fmaxf(x2, x3));
      float nm = fmaxf(m, mx);
      ss = ss * __expf(m - nm) + __expf(x0 - nm) + __expf(x1 - nm)
                               + __expf(x2 - nm) + __expf(x3 - nm);
      m = nm;
    }
    for (int off = 32; off; off >>= 1) {
      float mo = __shfl_xor(m, off), so = __shfl_xor(ss, off);
      float nm = fmaxf(m, mo);
      ss = ss * __expf(m - nm) + so * __expf(mo - nm);
      m = nm;
    }
    float uw = -LOGN - (m + __logf(ss));
    if (lane == 0) { us4[w] = uw; u[r0 + w] = uw; }
  }
  __syncthreads();
  // col partials over own 4 rows
  {
    float u0 = us4[0], u1 = us4[1], u2 = us4[2], u3 = us4[3];
    #pragma unroll 2
    for (int q = 0; q < 8; ++q) {
      int c = q * 256 + t;
      float x0 = Ks[c] + u0, x1 = Ks[N + c] + u1;
      float x2 = Ks[2 * N + c] + u2, x3 = Ks[3 * N + c] + u3;
      float m = fmaxf(fmaxf(x0, x1), fmaxf(x2, x3));
      float ss = __expf(x0 - m) + __expf(x1 - m) + __expf(x2 - m) + __expf(x3 - m);
      part[(size_t)blockIdx.x * N + c] = m + __logf(ss);
    }
  }
}

// combine 512 per-stripe partial LSEs -> v (128 blocks x 16 cols, 16 k-groups x 32 stripes)
__global__ __launch_bounds__(256) void k_comb(const float* __restrict__ part, float* __restrict__ v) {
  __shared__ float pp[16][17];
  const int t = threadIdx.x;
  const int cl = t & 15, kk = t >> 4;
  const int c = blockIdx.x * 16 + cl;
  float m = -INFINITY, s = 0.f;
  for (int k = kk * 32; k < kk * 32 + 32; ++k) {
    float x = part[(size_t)k * N + c];
    float nm = fmaxf(m, x);
    s = s * __expf(m - nm) + __expf(x - nm);
    m = nm;
  }
  pp[kk][cl] = m + __logf(s);
  __syncthreads();
  if (t < 16) {
    float m2 = -INFINITY, s2 = 0.f;
    #pragma unroll
    for (int g = 0; g < 16; ++g) {
      float x = pp[g][t];
      float nm = fmaxf(m2, x);
      s2 = s2 * __expf(m2 - nm) + __expf(x - nm);
      m2 = nm;
    }
    v[blockIdx.x * 16 + t] = -LOGN - (m2 + __logf(s2));
  }
}

// s = exp(K + u + v); rowsums -> as_, col partials -> bsp; fp16-scaled copy; optional s2 copy
__global__ __launch_bounds__(256) void k_swrite(const float* __restrict__ K, const float* __restrict__ u,
                                                const float* __restrict__ v, float* __restrict__ s,
                                                __half* __restrict__ sh,
                                                float* __restrict__ as_, float* __restrict__ bsp,
                                                float* __restrict__ s2) {
  __shared__ __align__(16) float vs[N];
  __shared__ __align__(16) float bc[N];
  int t = threadIdx.x;
  for (int j = t * 4; j < N; j += 1024) *(float4*)&vs[j] = *(const float4*)&v[j];
  __syncthreads();
  int lane = t & 63, w = t >> 6;
  float4 cacc[8];
  #pragma unroll
  for (int q = 0; q < 8; ++q) cacc[q] = make_float4(0.f, 0.f, 0.f, 0.f);
  int ibase = blockIdx.x * 8 + w * 2;
  for (int rr = 0; rr < 2; ++rr) {
    int i = ibase + rr;
    float ui = u[i];
    const float* Kr = K + (size_t)i * N;
    float* sr = s + (size_t)i * N;
    float rsum = 0.f;
    #pragma unroll
    for (int q = 0; q < 8; ++q) {
      int j = lane * 4 + q * 256;
      float4 kv = *(const float4*)&Kr[j];
      float4 sv;
      sv.x = __expf(kv.x + ui + vs[j]);
      sv.y = __expf(kv.y + ui + vs[j + 1]);
      sv.z = __expf(kv.z + ui + vs[j + 2]);
      sv.w = __expf(kv.w + ui + vs[j + 3]);
      *(float4*)&sr[j] = sv;
      __half2 h0 = __halves2half2(__float2half_rn(sv.x * SSCALE), __float2half_rn(sv.y * SSCALE));
      __half2 h1 = __halves2half2(__float2half_rn(sv.z * SSCALE), __float2half_rn(sv.w * SSCALE));
      uint2 pk; pk.x = *(u32*)&h0; pk.y = *(u32*)&h1;
      *(uint2*)&sh[(size_t)i * N + j] = pk;
      if (s2) *(float4*)&s2[(size_t)i * N + j] = sv;
      rsum += sv.x + sv.y + sv.z + sv.w;
      cacc[q].x += sv.x; cacc[q].y += sv.y; cacc[q].z += sv.z; cacc[q].w += sv.w;
    }
    for (int off = 32; off; off >>= 1) rsum += __shfl_down(rsum, off);
    if (lane == 0) as_[i] = rsum;
  }
  for (int ww = 0; ww < 4; ++ww) {
    if (w == ww) {
      #pragma unroll
      for (int q = 0; q < 8; ++q) {
        int j = lane * 4 + q * 256;
        if (ww == 0) *(float4*)&bc[j] = cacc[q];
        else {
          float4 old = *(float4*)&bc[j];
          old.x += cacc[q].x; old.y += cacc[q].y; old.z += cacc[q].z; old.w += cacc[q].w;
          *(float4*)&bc[j] = old;
        }
      }
    }
    __syncthreads();
  }
  float* bout = bsp + (size_t)blockIdx.x * N;
  for (int j = t * 4; j < N; j += 1024) *(float4*)&bout[j] = *(const float4*)&bc[j];
}

__global__ __launch_bounds__(256) void k_bscomb(const float* __restrict__ bsp, float* __restrict__ bs_) {
  int c = blockIdx.x * 256 + threadIdx.x;
  float acc = 0.f;
  for (int b = 0; b < 256; ++b) acc += bsp[(size_t)b * N + c];
  bs_[c] = acc;
}

// ---------------------------------------------------------------- final

// fused: sisr = inter.s row dots, yv = s.rs2 row dots, dotp[b] = block partial of M.s (scaled back)
__global__ __launch_bounds__(256) void k_fstats(const float* __restrict__ inter, const float* __restrict__ s,
                                                const float* __restrict__ M, const float* __restrict__ rs2,
                                                float* __restrict__ sisr, float* __restrict__ yv,
                                                double* __restrict__ dotp) {
  __shared__ __align__(16) float r2[N];
  __shared__ double redm[4];
  int t = threadIdx.x;
  for (int j = t * 4; j < N; j += 1024) *(float4*)&r2[j] = *(const float4*)&rs2[j];
  __syncthreads();
  int lane = t & 63, w = t >> 6;
  int i = blockIdx.x * 4 + w;
  const float* ir = inter + (size_t)i * N;
  const float* sr = s + (size_t)i * N;
  const float* mr = M + (size_t)i * N;
  float d1 = 0.f, d2 = 0.f;
  double dm = 0.0;
  for (int j = lane * 4; j < N; j += 256) {
    float4 iv = *(const float4*)&ir[j];
    float4 sv = *(const float4*)&sr[j];
    float4 mv = *(const float4*)&mr[j];
    d1 += iv.x * sv.x + iv.y * sv.y + iv.z * sv.z + iv.w * sv.w;
    d2 += sv.x * r2[j] + sv.y * r2[j + 1] + sv.z * r2[j + 2] + sv.w * r2[j + 3];
    dm += (double)(mv.x * sv.x) + (double)(mv.y * sv.y)
        + (double)(mv.z * sv.z) + (double)(mv.w * sv.w);
  }
  for (int off = 32; off; off >>= 1) {
    d1 += __shfl_down(d1, off);
    d2 += __shfl_down(d2, off);
    dm += __shfl_down(dm, off);
  }
  if (lane == 0) { sisr[i] = d1; yv[i] = d2; redm[w] = dm; }
  __syncthreads();
  if (t == 0) dotp[blockIdx.x] = (redm[0] + redm[1] + redm[2] + redm[3]) * (double)ISCALE;
}

__global__ __launch_bounds__(256) void k_final(
    const float* __restrict__ paf, const float* __restrict__ pbf,
    const float* __restrict__ r1sq, const float* __restrict__ r2sq,
    const float* __restrict__ rs1, const float* __restrict__ rs2,
    const float* __restrict__ as_, const float* __restrict__ bs_,
    const float* __restrict__ yv, const float* __restrict__ sisr,
    const double* __restrict__ k1p, const double* __restrict__ dotp,
    const float* __restrict__ lamp, float* __restrict__ out_loss, float* __restrict__ out_lam) {
  __shared__ double red[256];
  int t = threadIdx.x;
  auto dred = [&](double acc) -> double {
    red[t] = acc; __syncthreads();
    for (int off = 128; off; off >>= 1) { if (t < off) red[t] += red[t + off]; __syncthreads(); }
    double r = red[0]; __syncthreads();
    return r;
  };
  auto dotv = [&](const float* a, const float* b) -> double {
    double acc = 0.0;
    for (int k = t; k < N; k += 256) acc += (double)a[k] * (b ? (double)b[k] : 1.0);
    return dred(acc);
  };
  double k1a = 0.0;
  for (int k = t; k < 1024; k += 256) k1a += k1p[k];
  double k1 = dred(k1a);
  double sma = 0.0;
  for (int k = t; k < 512; k += 256) sma += dotp[k];
  double smfs = dred(sma);
  double paas = dotv(paf, as_);
  double pbbs = dotv(pbf, bs_);
  double r1as = dotv(r1sq, as_);
  double c2bs = dotv(r2sq, bs_);
  double rs1y = dotv(rs1, yv);
  double sis  = dotv(sisr, nullptr);
  double sr1  = dotv(r1sq, nullptr);
  double sr2  = dotv(r2sq, nullptr);
  double ss1  = dotv(rs1, nullptr);
  double ss2  = dotv(rs2, nullptr);
  if (t == 0) {
    double lam0 = (double)*lamp;
    double k2 = 2048.0 * r1as + 2048.0 * c2bs - 2.0 * rs1y;
    double k3 = 2048.0 * 2048.0 * (sr1 + sr2) - 2.0 * ss1 * ss2;
    double upd = (k1 + 40.0 * k2) / (40.0 * k3);
    double lamn = 0.01 * upd + 0.99 * lam0;
    double g1 = paas + pbbs - 2.0 * smfs;
    double wl = sis - lamn * k1;
    double gwl = g1 - 2.0 * lamn * k2 + lamn * lamn * k3;
    double loss = wl + 20.0 * gwl + 20.0;
    *out_loss = (float)loss;
    *out_lam = (float)lamn;
  }
}

// ---------------------------------------------------------------- launch

extern "C" void kernel_launch(void* const* d_in, const int* in_sizes, int n_in,
                              void* d_out, int out_size, void* d_ws, size_t ws_size,
                              hipStream_t stream) {
  (void)in_sizes; (void)n_in; (void)out_size; (void)ws_size;
  const float* out1 = (const float*)d_in[0];
  const float* out2 = (const float*)d_in[1];
  const float* adj1 = (const float*)d_in[2];
  const float* adj2 = (const float*)d_in[3];
  const float* lamp = (const float*)d_in[4];
  float* o = (float*)d_out;

  char* w = (char*)d_ws;
  size_t off = 0;
  auto alloc = [&](size_t bytes) -> void* {
    void* p = w + off;
    off = (off + bytes + 255) & ~(size_t)255;
    return p;
  };
  const size_t NNf = (size_t)N * N * sizeof(float);
  float* inter = (float*)alloc(NNf);
  float* Mbuf  = (float*)alloc(NNf);
  float* Kbuf  = (float*)alloc(NNf);
  float* sbuf  = (float*)alloc(NNf);
  __half* sh   = (__half*)alloc((size_t)N * N * sizeof(__half));
  __half* Tth  = (__half*)alloc((size_t)N * N * sizeof(__half));
  int* rp1   = (int*)alloc((N + 1) * sizeof(int));
  int* rp2   = (int*)alloc((N + 1) * sizeof(int));
  int* cnt   = (int*)alloc(N * sizeof(int));
  int* cols1 = (int*)alloc(CAP * sizeof(int));
  int* rows1 = (int*)alloc(CAP * sizeof(int));
  int* cols2 = (int*)alloc(CAP * sizeof(int));
  int* rows2 = (int*)alloc(CAP * sizeof(int));
  float* vals1 = (float*)alloc(CAP * sizeof(float));
  float* vals2 = (float*)alloc(CAP * sizeof(float));
  float* r1sq = (float*)alloc(N * sizeof(float));
  float* rs1  = (float*)alloc(N * sizeof(float));
  float* r2sq = (float*)alloc(N * sizeof(float));
  float* rs2v = (float*)alloc(N * sizeof(float));
  float* asv  = (float*)alloc(N * sizeof(float));
  float* bsv  = (float*)alloc(N * sizeof(float));
  float* uv   = (float*)alloc(N * sizeof(float));
  float* vv   = (float*)alloc(N * sizeof(float));
  float* Ai   = (float*)alloc(N * sizeof(float));
  float* Bj   = (float*)alloc(N * sizeof(float));
  float* RLi  = (float*)alloc(N * sizeof(float));
  float* yv   = (float*)alloc(N * sizeof(float));
  float* sisr = (float*)alloc(N * sizeof(float));
  float* part = (float*)alloc((size_t)512 * N * sizeof(float));
  float* bsp  = (float*)alloc((size_t)256 * N * sizeof(float));
  double* k1p = (double*)alloc(1024 * sizeof(double));
  double* dotp= (double*)alloc(512 * sizeof(double));

  dim3 b(256);

  // ---- precompute
  k_gemm_inter<<<dim3(32, 32), b, 0, stream>>>(out1, out2, inter, k1p);
  k_count<<<512, b, 0, stream>>>(adj1, cnt);
  k_scan<<<1, b, 0, stream>>>(cnt, rp1);
  k_count<<<512, b, 0, stream>>>(adj2, cnt);
  k_scan<<<1, b, 0, stream>>>(cnt, rp2);
  k_fill<<<512, b, 0, stream>>>(adj1, rp1, cols1, rows1);
  k_fill<<<512, b, 0, stream>>>(adj2, rp2, cols2, rows2);
  k_vals<<<2048, b, 0, stream>>>(rp1, rows1, cols1, vals1, out1);
  k_vals<<<2048, b, 0, stream>>>(rp2, rows2, cols2, vals2, out2);
  k_rowstats<<<512, b, 0, stream>>>(rp1, vals1, rs1, r1sq);
  k_rowstats<<<512, b, 0, stream>>>(rp2, vals2, rs2v, r2sq);

  // ---- outer loop
  for (int t = 0; t < 10; ++t) {
    k_prep<<<24, b, 0, stream>>>((t == 0) ? 0 : 1, rp1, cols1, vals1, rp2, cols2, vals2,
                                 r1sq, rs1, r2sq, rs2v, asv, bsv, lamp, Ai, Bj, RLi, vv);
    if (t > 0) {
      k_spmmt<true><<<2048, b, 0, stream>>>(rp1, cols1, vals1, sh, Tth, nullptr);
      k_spmmt<false><<<2048, b, 0, stream>>>(rp2, cols2, vals2, Tth, nullptr, Mbuf);
      k_sink<1><<<512, b, 0, stream>>>(Kbuf, Kbuf, inter, Mbuf, Ai, Bj, RLi, rs2v, vv, uv, part);
    } else {
      k_sink<2><<<512, b, 0, stream>>>(Kbuf, Kbuf, inter, Mbuf, Ai, Bj, RLi, rs2v, vv, uv, part);
    }
    k_comb<<<128, b, 0, stream>>>(part, vv);
    for (int r = 1; r < 5; ++r) {
      k_sink<0><<<512, b, 0, stream>>>(Kbuf, Kbuf, inter, Mbuf, Ai, Bj, RLi, rs2v, vv, uv, part);
      k_comb<<<128, b, 0, stream>>>(part, vv);
    }
    k_swrite<<<256, b, 0, stream>>>(Kbuf, uv, vv, sbuf, sh, asv, bsp, (t == 9) ? (o + 1) : nullptr);
    k_bscomb<<<8, b, 0, stream>>>(bsp, bsv);
  }

  // ---- final: lambda update + loss
  k_spmmt<true><<<2048, b, 0, stream>>>(rp1, cols1, vals1, sh, Tth, nullptr);
  k_spmmt<false><<<2048, b, 0, stream>>>(rp2, cols2, vals2, Tth, nullptr, Mbuf);
  k_prep<<<24, b, 0, stream>>>(2, rp1, cols1, vals1, rp2, cols2, vals2,
                               r1sq, rs1, r2sq, rs2v, asv, bsv, lamp, Ai, Bj, RLi, vv);
  k_fstats<<<512, b, 0, stream>>>(inter, sbuf, Mbuf, rs2v, sisr, yv, dotp);
  k_final<<<1, b, 0, stream>>>(Ai, Bj, r1sq, r2sq, rs1, rs2v, asv, bsv, yv, sisr,
                               k1p, dotp, lamp, o, o + 1 + (size_t)N * N);
}